// Round 3
// 4122.791 us; speedup vs baseline: 1.3807x; 1.3807x over previous
//
#include <hip/hip_runtime.h>

// LSTM-with-projection (ELMo LSTMP), persistent-kernel, fp32-class precision.
// Round 11: Round-9/10 architecture (local rank-16 projection partials + flat
// 256-block reduction) with TWO fixes:
//  1. Partials are f32 (not f16). The recurrence has per-step gain >1, which
//     amplifies per-step noise ~2e3x over 128 steps; f16 partials (eps~8e-4)
//     decohered to absmax ~3.8. f32 restores round-8-class noise (~1e-5).
//  2. Only round-8-proven agent primitives: 4-byte stg_dev/stg_dev_u32 stores
//     and u32/u64 (ldg_dev8) agent loads. No 8-byte atomic stores.
// Partials are stored directly from D-frag registers (no LDS staging): each
// 16-lane group writes a 64B segment -> adequate coalescing, frees the zb
// overlay hazard entirely.

#define NBLK 256
#define NTHR 512
#define B_   32
#define S_   128
#define D_   512
#define U_   4096
#define PJ   512
#define G4   16384
#define PITC 520
#define LSCALE 2048.0f
#define LINV   4.8828125e-4f   // 1/2048

typedef __attribute__((ext_vector_type(8))) _Float16 half8;
typedef __attribute__((ext_vector_type(4))) float floatx4;

__device__ __forceinline__ void split_h(float f, _Float16& hi, _Float16& lo) {
  _Float16 h = (_Float16)f;                  // RTNE
  hi = h;
  lo = (_Float16)((f - (float)h) * LSCALE);  // residual x2048: fp16-normal
}

// ---- agent-scope ops: LLC-coherent, no fences needed (round-8 proven) ----
__device__ __forceinline__ void stg_dev(float* p, float v) {
  __hip_atomic_store(p, v, __ATOMIC_RELAXED, __HIP_MEMORY_SCOPE_AGENT);
}
__device__ __forceinline__ void stg_dev_u32(unsigned* p, unsigned v) {
  __hip_atomic_store(p, v, __ATOMIC_RELAXED, __HIP_MEMORY_SCOPE_AGENT);
}
__device__ __forceinline__ unsigned ldg_dev_u32(const unsigned* p) {
  return __hip_atomic_load(p, __ATOMIC_RELAXED, __HIP_MEMORY_SCOPE_AGENT);
}
__device__ __forceinline__ float2 ldg_dev8(const float* p) {
  unsigned long long v = __hip_atomic_load((const unsigned long long*)p,
                                           __ATOMIC_RELAXED,
                                           __HIP_MEMORY_SCOPE_AGENT);
  union { unsigned long long u; float2 f; } c; c.u = v; return c.f;
}

__global__ __launch_bounds__(NTHR, 2)
void lstm_persistent(const float* __restrict__ x,
                     const float* __restrict__ Wk,
                     const float* __restrict__ R,
                     const float* __restrict__ bias,
                     const float* __restrict__ P,
                     float* __restrict__ out,
                     unsigned* __restrict__ grpCnt1,   // 32 x 128B lines
                     unsigned* __restrict__ grpDone1,  // 32 x 128B lines
                     unsigned* __restrict__ grpCnt2,   // 32 x 128B lines
                     unsigned* __restrict__ grpDone2,  // 32 x 128B lines
                     float* __restrict__ hbuf,         // [32][512] f32
                     float* __restrict__ partial)      // f32 [256][32][512]
{
  __shared__ __align__(16) char smem[100352];
  _Float16* xh_hi = (_Float16*)smem;                        // 32*520 halves
  _Float16* xh_lo = xh_hi + B_ * PITC;
  float (*zb)[64][33] = (float (*)[64][33])(smem + 66560);  // [4][64][33]
  __shared__ float cst[512];
  __shared__ float biasL[64];
  __shared__ _Float16 hph[1024], hpl[1024];   // hp split planes [32][32], k>=16 stays 0
  __shared__ float2 redf[512];                // [16 grp][32] reduction scratch

  const int tid  = threadIdx.x;
  const int blk  = blockIdx.x;
  const int lane = tid & 63;
  const int w    = tid >> 6;   // wave 0..7
  const int ch   = w & 1;      // phase A col-half
  const int sq   = w >> 1;     // phase A k-quarter
  const int g    = blk >> 3;   // barrier group

  // ---- one-time setup -------------------------------------------------
  if (tid < 64) {
    int gg = tid >> 4, j = tid & 15;
    biasL[tid] = bias[gg * U_ + blk * 16 + j];
  }
  cst[tid] = 0.f;
  for (int i = tid; i < 1024; i += NTHR) { hph[i] = (_Float16)0.f; hpl[i] = (_Float16)0.f; }

  // Phase A weight B-fragments (split fp16) into registers.
  half8 bhi[2][2][4], blo[2][2][4];
  {
    const int n = lane & 15, q = lane >> 4;
#pragma unroll
    for (int c = 0; c < 2; ++c) {
      const float* Wsrc = c ? R : Wk;
#pragma unroll
      for (int nt = 0; nt < 2; ++nt) {
        int cib  = ch * 32 + nt * 16 + n;
        int gcol = (cib >> 4) * U_ + blk * 16 + (cib & 15);
#pragma unroll
        for (int u = 0; u < 4; ++u) {
          half8 th, tl;
#pragma unroll
          for (int i = 0; i < 8; ++i) {
            int k = (sq * 4 + u) * 32 + q * 8 + i;
            _Float16 hi, lo;
            split_h(Wsrc[(size_t)k * G4 + gcol], hi, lo);
            th[i] = hi; tl[i] = lo;
          }
          bhi[nt][c][u] = th;
          blo[nt][c][u] = tl;
        }
      }
    }
  }

  // Projection B-fragments: P rows blk*16..+15 (K padded to 32 with zeros),
  // wave w owns cols w*64..w*64+63 (4 n-tiles). 16 VGPRs total.
  half8 psh[4], psl[4];
  {
    const int n = lane & 15, q = lane >> 4;
#pragma unroll
    for (int nt = 0; nt < 4; ++nt) {
      half8 th, tl;
#pragma unroll
      for (int i = 0; i < 8; ++i) { th[i] = (_Float16)0.f; tl[i] = (_Float16)0.f; }
      if (q < 2) {
#pragma unroll
        for (int i = 0; i < 8; ++i) {
          int k = q * 8 + i;                      // 0..15 real K
          _Float16 hi, lo;
          split_h(P[(size_t)(blk * 16 + k) * PJ + (w * 64 + nt * 16 + n)], hi, lo);
          th[i] = hi; tl[i] = lo;
        }
      }
      psh[nt] = th; psl[nt] = tl;
    }
  }
  __syncthreads();

  const int rb = blk >> 3;        // reduction duty: batch
  const int rn = (blk & 7) << 6;  // reduction duty: col base (64 cols)

  // ---- time loop ------------------------------------------------------
  for (int t = 0; t < S_; ++t) {
    // ===== A) reduction duty for step t-1 =====
    if (t > 0) {
      const unsigned e = (unsigned)t;
      if (w == 0) {
        for (;;) {
          unsigned v = (lane < 32) ? ldg_dev_u32(grpDone1 + lane * 32) : e;
          if (__all((int)(v >= e))) break;
          __builtin_amdgcn_s_sleep(2);
        }
      }
      __syncthreads();
      {
        const int o2 = tid & 31, gg = tid >> 5;
        const float* pb = partial + (size_t)rb * PJ + rn + 2 * o2;
        float s0 = 0.f, s1 = 0.f;
#pragma unroll
        for (int k = 0; k < 16; ++k) {
          float2 v = ldg_dev8(pb + (size_t)(gg + k * 16) * 16384);
          s0 += v.x;
          s1 += v.y;
        }
        redf[gg * 32 + o2] = make_float2(s0, s1);
      }
      __syncthreads();
      if (tid < 32) {
        float a0 = 0.f, a1 = 0.f;
#pragma unroll
        for (int g2 = 0; g2 < 16; ++g2) {
          float2 v = redf[g2 * 32 + tid];
          a0 += v.x; a1 += v.y;
        }
        a0 = fminf(fmaxf(a0, -3.f), 3.f);
        a1 = fminf(fmaxf(a1, -3.f), 3.f);
        stg_dev(hbuf + rb * PJ + rn + 2 * tid,     a0);
        stg_dev(hbuf + rb * PJ + rn + 2 * tid + 1, a1);
        float* op = out + ((size_t)rb * S_ + (t - 1)) * PJ + rn + 2 * tid;
        stg_dev(op,     a0);
        stg_dev(op + 1, a1);
      }
      __syncthreads();   // drain hbuf/out stores before arrive2
      if (tid == 0) {
        unsigned old = __hip_atomic_fetch_add(grpCnt2 + g * 32, 1u,
                           __ATOMIC_RELAXED, __HIP_MEMORY_SCOPE_AGENT);
        if (old == e * 8u - 1u)
          stg_dev_u32(grpDone2 + g * 32, e);
      }
    }

    // ===== B) chunk 0: x_t (independent of h) — overlaps h-ready wait =====
    floatx4 acc00 = {0.f, 0.f, 0.f, 0.f};
    floatx4 acc01 = acc00, acc10 = acc00, acc11 = acc00;
    floatx4 accL00 = acc00, accL01 = acc00, accL10 = acc00, accL11 = acc00;
    const int m_ = lane & 15, q = lane >> 4;

#pragma unroll
    for (int it = 0; it < 4; ++it) {
      int c8 = tid + it * NTHR;
      int b  = c8 >> 6;
      int kg = (c8 & 63) << 3;
      const float* src = x + (size_t)(b * S_ + t) * D_ + kg;   // normal: cached
      float4 f0 = *(const float4*)src;
      float4 f1 = *(const float4*)(src + 4);
      half8 th, tl; _Float16 hi, lo;
      split_h(f0.x, hi, lo); th[0] = hi; tl[0] = lo;
      split_h(f0.y, hi, lo); th[1] = hi; tl[1] = lo;
      split_h(f0.z, hi, lo); th[2] = hi; tl[2] = lo;
      split_h(f0.w, hi, lo); th[3] = hi; tl[3] = lo;
      split_h(f1.x, hi, lo); th[4] = hi; tl[4] = lo;
      split_h(f1.y, hi, lo); th[5] = hi; tl[5] = lo;
      split_h(f1.z, hi, lo); th[6] = hi; tl[6] = lo;
      split_h(f1.w, hi, lo); th[7] = hi; tl[7] = lo;
      *(half8*)(xh_hi + b * PITC + kg) = th;
      *(half8*)(xh_lo + b * PITC + kg) = tl;
    }
    __syncthreads();
#pragma unroll
    for (int u = 0; u < 4; ++u) {
      int ko = (sq * 4 + u) * 32 + q * 8;
      half8 ah0 = *(const half8*)(xh_hi + m_ * PITC + ko);
      half8 ah1 = *(const half8*)(xh_hi + (16 + m_) * PITC + ko);
      half8 al0 = *(const half8*)(xh_lo + m_ * PITC + ko);
      half8 al1 = *(const half8*)(xh_lo + (16 + m_) * PITC + ko);
      acc00 = __builtin_amdgcn_mfma_f32_16x16x32_f16(ah0, bhi[0][0][u], acc00, 0, 0, 0);
      acc01 = __builtin_amdgcn_mfma_f32_16x16x32_f16(ah0, bhi[1][0][u], acc01, 0, 0, 0);
      acc10 = __builtin_amdgcn_mfma_f32_16x16x32_f16(ah1, bhi[0][0][u], acc10, 0, 0, 0);
      acc11 = __builtin_amdgcn_mfma_f32_16x16x32_f16(ah1, bhi[1][0][u], acc11, 0, 0, 0);
      accL00 = __builtin_amdgcn_mfma_f32_16x16x32_f16(ah0, blo[0][0][u], accL00, 0, 0, 0);
      accL01 = __builtin_amdgcn_mfma_f32_16x16x32_f16(ah0, blo[1][0][u], accL01, 0, 0, 0);
      accL10 = __builtin_amdgcn_mfma_f32_16x16x32_f16(ah1, blo[0][0][u], accL10, 0, 0, 0);
      accL11 = __builtin_amdgcn_mfma_f32_16x16x32_f16(ah1, blo[1][0][u], accL11, 0, 0, 0);
      accL00 = __builtin_amdgcn_mfma_f32_16x16x32_f16(al0, bhi[0][0][u], accL00, 0, 0, 0);
      accL01 = __builtin_amdgcn_mfma_f32_16x16x32_f16(al0, bhi[1][0][u], accL01, 0, 0, 0);
      accL10 = __builtin_amdgcn_mfma_f32_16x16x32_f16(al1, bhi[0][0][u], accL10, 0, 0, 0);
      accL11 = __builtin_amdgcn_mfma_f32_16x16x32_f16(al1, bhi[1][0][u], accL11, 0, 0, 0);
    }

    // ===== C) wait h(t-1) ready (grpDone2 >= t) =====
    if (t > 0) {
      if (w == 0) {
        const unsigned e = (unsigned)t;
        for (;;) {
          unsigned v = (lane < 32) ? ldg_dev_u32(grpDone2 + lane * 32) : e;
          if (__all((int)(v >= e))) break;
          __builtin_amdgcn_s_sleep(2);
        }
      }
    }
    __syncthreads();   // also protects xh from still-running chunk0 MFMA readers

    // ===== D) chunk 1: h =====
#pragma unroll
    for (int it = 0; it < 4; ++it) {
      int c8 = tid + it * NTHR;
      int b  = c8 >> 6;
      int kg = (c8 & 63) << 3;
      const float* src = hbuf + b * PJ + kg;     // agent: LLC-coherent
      float2 g0 = ldg_dev8(src);
      float2 g1 = ldg_dev8(src + 2);
      float2 g2 = ldg_dev8(src + 4);
      float2 g3 = ldg_dev8(src + 6);
      float f[8] = {g0.x, g0.y, g1.x, g1.y, g2.x, g2.y, g3.x, g3.y};
      half8 th, tl;
#pragma unroll
      for (int i = 0; i < 8; ++i) {
        _Float16 hi, lo;
        split_h(f[i], hi, lo);
        th[i] = hi; tl[i] = lo;
      }
      *(half8*)(xh_hi + b * PITC + kg) = th;
      *(half8*)(xh_lo + b * PITC + kg) = tl;
    }
    __syncthreads();
#pragma unroll
    for (int u = 0; u < 4; ++u) {
      int ko = (sq * 4 + u) * 32 + q * 8;
      half8 ah0 = *(const half8*)(xh_hi + m_ * PITC + ko);
      half8 ah1 = *(const half8*)(xh_hi + (16 + m_) * PITC + ko);
      half8 al0 = *(const half8*)(xh_lo + m_ * PITC + ko);
      half8 al1 = *(const half8*)(xh_lo + (16 + m_) * PITC + ko);
      acc00 = __builtin_amdgcn_mfma_f32_16x16x32_f16(ah0, bhi[0][1][u], acc00, 0, 0, 0);
      acc01 = __builtin_amdgcn_mfma_f32_16x16x32_f16(ah0, bhi[1][1][u], acc01, 0, 0, 0);
      acc10 = __builtin_amdgcn_mfma_f32_16x16x32_f16(ah1, bhi[0][1][u], acc10, 0, 0, 0);
      acc11 = __builtin_amdgcn_mfma_f32_16x16x32_f16(ah1, bhi[1][1][u], acc11, 0, 0, 0);
      accL00 = __builtin_amdgcn_mfma_f32_16x16x32_f16(ah0, blo[0][1][u], accL00, 0, 0, 0);
      accL01 = __builtin_amdgcn_mfma_f32_16x16x32_f16(ah0, blo[1][1][u], accL01, 0, 0, 0);
      accL10 = __builtin_amdgcn_mfma_f32_16x16x32_f16(ah1, blo[0][1][u], accL10, 0, 0, 0);
      accL11 = __builtin_amdgcn_mfma_f32_16x16x32_f16(ah1, blo[1][1][u], accL11, 0, 0, 0);
      accL00 = __builtin_amdgcn_mfma_f32_16x16x32_f16(al0, bhi[0][1][u], accL00, 0, 0, 0);
      accL01 = __builtin_amdgcn_mfma_f32_16x16x32_f16(al0, bhi[1][1][u], accL01, 0, 0, 0);
      accL10 = __builtin_amdgcn_mfma_f32_16x16x32_f16(al1, bhi[0][1][u], accL10, 0, 0, 0);
      accL11 = __builtin_amdgcn_mfma_f32_16x16x32_f16(al1, bhi[1][1][u], accL11, 0, 0, 0);
    }

    // D-frag -> zb[sq][col][batch]  (no sync needed: zb disjoint from xh)
    {
      int n  = lane & 15;
      int c0 = ch * 32 + n, c1 = ch * 32 + 16 + n;
      int r0 = q * 4,       r1 = 16 + q * 4;
#pragma unroll
      for (int i = 0; i < 4; ++i) {
        zb[sq][c0][r0 + i] = acc00[i] + accL00[i] * LINV;
        zb[sq][c1][r0 + i] = acc01[i] + accL01[i] * LINV;
        zb[sq][c0][r1 + i] = acc10[i] + accL10[i] * LINV;
        zb[sq][c1][r1 + i] = acc11[i] + accL11[i] * LINV;
      }
    }
    __syncthreads();

    // ===== E) gates + cell update; hp -> LDS split planes =====
    {
      int p = tid;                      // 0..511
      int b = p >> 4, j = p & 15;
      float zi = zb[0][j][b] + zb[1][j][b] + zb[2][j][b] + zb[3][j][b] + biasL[j];
      float zf = zb[0][16+j][b] + zb[1][16+j][b] + zb[2][16+j][b] + zb[3][16+j][b] + biasL[16+j];
      float zc = zb[0][32+j][b] + zb[1][32+j][b] + zb[2][32+j][b] + zb[3][32+j][b] + biasL[32+j];
      float zo = zb[0][48+j][b] + zb[1][48+j][b] + zb[2][48+j][b] + zb[3][48+j][b] + biasL[48+j];
      float ig = fminf(fmaxf(0.2f * zi + 0.5f, 0.f), 1.f);
      float fg = fminf(fmaxf(0.2f * zf + 0.5f, 0.f), 1.f);
      float og = fminf(fmaxf(0.2f * zo + 0.5f, 0.f), 1.f);
      float cn = fg * cst[p] + ig * tanhf(zc);
      float hp = og * tanhf(cn);                 // uses UNCLIPPED c
      cst[p] = fminf(fmaxf(cn, -3.f), 3.f);      // cell clip

      _Float16 hh, hl;
      split_h(hp, hh, hl);
      hph[b * 32 + j] = hh;
      hpl[b * 32 + j] = hl;
    }
    __syncthreads();   // hph/hpl visible to all waves

    // ===== F) local projection partial: hp[32,16] @ P[16,512] (K padded 32)
    //          D-frags stored DIRECTLY to f32 partial (no LDS staging) =====
    {
      floatx4 pa[2][4], pL[2][4];
#pragma unroll
      for (int mt = 0; mt < 2; ++mt)
#pragma unroll
        for (int nt = 0; nt < 4; ++nt) {
          pa[mt][nt] = (floatx4){0.f, 0.f, 0.f, 0.f};
          pL[mt][nt] = (floatx4){0.f, 0.f, 0.f, 0.f};
        }
#pragma unroll
      for (int mt = 0; mt < 2; ++mt) {
        half8 ah = *(const half8*)(hph + (mt * 16 + m_) * 32 + q * 8);
        half8 al = *(const half8*)(hpl + (mt * 16 + m_) * 32 + q * 8);
#pragma unroll
        for (int nt = 0; nt < 4; ++nt) {
          pa[mt][nt] = __builtin_amdgcn_mfma_f32_16x16x32_f16(ah, psh[nt], pa[mt][nt], 0, 0, 0);
          pL[mt][nt] = __builtin_amdgcn_mfma_f32_16x16x32_f16(ah, psl[nt], pL[mt][nt], 0, 0, 0);
          pL[mt][nt] = __builtin_amdgcn_mfma_f32_16x16x32_f16(al, psh[nt], pL[mt][nt], 0, 0, 0);
        }
      }
      float* pout = partial + (size_t)blk * 16384;   // [32][512] f32
#pragma unroll
      for (int mt = 0; mt < 2; ++mt)
#pragma unroll
        for (int nt = 0; nt < 4; ++nt)
#pragma unroll
          for (int i = 0; i < 4; ++i) {
            float v = pa[mt][nt][i] + pL[mt][nt][i] * LINV;
            stg_dev(pout + (mt * 16 + q * 4 + i) * PJ + w * 64 + nt * 16 + m_, v);
          }
    }
    __syncthreads();   // drain partial stores before arrival

    if (tid == 0) {
      unsigned old = __hip_atomic_fetch_add(grpCnt1 + g * 32, 1u,
                         __ATOMIC_RELAXED, __HIP_MEMORY_SCOPE_AGENT);
      if (old == (unsigned)(t + 1) * 8u - 1u)
        stg_dev_u32(grpDone1 + g * 32, (unsigned)(t + 1));
    }
  }

  // ===== epilogue: reduction duty for t = S_-1 (out only) =====
  {
    const unsigned e = (unsigned)S_;
    if (w == 0) {
      for (;;) {
        unsigned v = (lane < 32) ? ldg_dev_u32(grpDone1 + lane * 32) : e;
        if (__all((int)(v >= e))) break;
        __builtin_amdgcn_s_sleep(2);
      }
    }
    __syncthreads();
    {
      const int o2 = tid & 31, gg = tid >> 5;
      const float* pb = partial + (size_t)rb * PJ + rn + 2 * o2;
      float s0 = 0.f, s1 = 0.f;
#pragma unroll
      for (int k = 0; k < 16; ++k) {
        float2 v = ldg_dev8(pb + (size_t)(gg + k * 16) * 16384);
        s0 += v.x;
        s1 += v.y;
      }
      redf[gg * 32 + o2] = make_float2(s0, s1);
    }
    __syncthreads();
    if (tid < 32) {
      float a0 = 0.f, a1 = 0.f;
#pragma unroll
      for (int g2 = 0; g2 < 16; ++g2) {
        float2 v = redf[g2 * 32 + tid];
        a0 += v.x; a1 += v.y;
      }
      a0 = fminf(fmaxf(a0, -3.f), 3.f);
      a1 = fminf(fmaxf(a1, -3.f), 3.f);
      float* op = out + ((size_t)rb * S_ + (S_ - 1)) * PJ + rn + 2 * tid;
      stg_dev(op,     a0);
      stg_dev(op + 1, a1);
    }
  }
}

extern "C" void kernel_launch(void* const* d_in, const int* in_sizes, int n_in,
                              void* d_out, int out_size, void* d_ws, size_t ws_size,
                              hipStream_t stream) {
  const float* x_   = (const float*)d_in[0];
  const float* Wk   = (const float*)d_in[1];
  const float* R_   = (const float*)d_in[2];
  const float* bias = (const float*)d_in[3];
  const float* P_   = (const float*)d_in[4];
  float* out = (float*)d_out;

  unsigned char* ws = (unsigned char*)d_ws;
  unsigned* grpCnt1  = (unsigned*)ws;                 // 4 KB (32 lines)
  unsigned* grpDone1 = (unsigned*)(ws + 4096);        // 4 KB
  unsigned* grpCnt2  = (unsigned*)(ws + 8192);        // 4 KB
  unsigned* grpDone2 = (unsigned*)(ws + 12288);       // 4 KB
  float* hbuf        = (float*)(ws + 16384);          // 64 KB
  float* partial     = (float*)(ws + 16384 + 65536);  // 16 MB f32 partials

  // zero flags + initial h every launch
  (void)hipMemsetAsync(d_ws, 0, 16384 + 65536, stream);

  lstm_persistent<<<dim3(NBLK), dim3(NTHR), 0, stream>>>(
      x_, Wk, R_, bias, P_, out, grpCnt1, grpDone1, grpCnt2, grpDone2,
      hbuf, partial);
}

// Round 4
// 2663.393 us; speedup vs baseline: 2.1373x; 1.5479x over previous
//
#include <hip/hip_runtime.h>

// LSTM-with-projection (ELMo LSTMP), persistent-kernel, fp32-class precision.
// Round 12: attack the fabric-transaction bound (r11: 49MB/step of 4-8B sc1
// transactions = 31us/step).
//  1. All bulk sc1 paths widened to 16B via inline asm (same sc1 policy the
//     agent-scope builtins emit): partial staged in LDS (overlay dead xh) ->
//     8 coalesced dwordx4 sc1 stores/thread; reduction = 8 pipelined dwordx4
//     sc1 loads/thread + one vmcnt(0) + sched_barrier (rule: compiler may
//     hoist register uses past asm waitcnt).
//  2. hbuf is a 128-slot ring (one fresh 64KB slot per step): consumers read
//     h with NORMAL cached loads -> per-XCD L2 absorbs the 32x broadcast
//     (16MB/step -> ~0.5MB/step fabric). Slot addresses never reused within
//     a launch; cross-launch reuse is bit-identical data (benign).
//  3. Flat per-block flags (256 u32): writer = 1 sc1 store; poller = w0,
//     1x16B sc1 load per lane covering 4 flags. No fetch_add, no leader hop.
//  4. x-stage+MFMA hoisted before the partials-ready wait (hides producer
//     store-drain tail).

#define NBLK 256
#define NTHR 512
#define B_   32
#define S_   128
#define D_   512
#define U_   4096
#define PJ   512
#define G4   16384
#define PITC 520
#define LSCALE 2048.0f
#define LINV   4.8828125e-4f   // 1/2048

typedef __attribute__((ext_vector_type(8))) _Float16 half8;
typedef __attribute__((ext_vector_type(4))) float floatx4;
typedef __attribute__((ext_vector_type(4))) unsigned int uintx4;

__device__ __forceinline__ void split_h(float f, _Float16& hi, _Float16& lo) {
  _Float16 h = (_Float16)f;                  // RTNE
  hi = h;
  lo = (_Float16)((f - (float)h) * LSCALE);  // residual x2048: fp16-normal
}

// ---- agent-scope (sc1) ops: LLC-coherent ----
__device__ __forceinline__ void stg_dev_u32(unsigned* p, unsigned v) {
  __hip_atomic_store(p, v, __ATOMIC_RELAXED, __HIP_MEMORY_SCOPE_AGENT);
}
__device__ __forceinline__ void store16_sc1(float* p, floatx4 v) {
  asm volatile("global_store_dwordx4 %0, %1, off sc1" :: "v"(p), "v"(v) : "memory");
}
__device__ __forceinline__ uintx4 ld16u_sc1(const unsigned* p) {
  uintx4 r;
  asm volatile("global_load_dwordx4 %0, %1, off sc1\n\ts_waitcnt vmcnt(0)"
               : "=v"(r) : "v"(p) : "memory");
  return r;
}

__global__ __launch_bounds__(NTHR, 2)
void lstm_persistent(const float* __restrict__ x,
                     const float* __restrict__ Wk,
                     const float* __restrict__ R,
                     const float* __restrict__ bias,
                     const float* __restrict__ P,
                     float* __restrict__ out,
                     unsigned* __restrict__ flags1,   // [256] u32: partials ready
                     unsigned* __restrict__ flags2,   // [256] u32: h ready
                     float* __restrict__ hbuf,        // ring [128][32][512] f32
                     float* __restrict__ partial)     // f32 [256][32][512]
{
  __shared__ __align__(16) char smem[100352];
  _Float16* xh_hi = (_Float16*)smem;                        // 32*520 halves
  _Float16* xh_lo = xh_hi + B_ * PITC;
  float (*zb)[64][33] = (float (*)[64][33])(smem + 66560);  // [4][64][33]
  float* part_lds = (float*)smem;            // overlays xh (64KB), phase F only
  __shared__ float cst[512];
  __shared__ float biasL[64];
  __shared__ _Float16 hph[1024], hpl[1024];  // hp split planes [32][32], k>=16 = 0
  __shared__ floatx4 redf4[512];             // [32 gg][16 o4] reduction scratch

  const int tid  = threadIdx.x;
  const int blk  = blockIdx.x;
  const int lane = tid & 63;
  const int w    = tid >> 6;   // wave 0..7
  const int ch   = w & 1;      // phase A col-half
  const int sq   = w >> 1;     // phase A k-quarter

  // ---- one-time setup -------------------------------------------------
  if (tid < 64) {
    int gg = tid >> 4, j = tid & 15;
    biasL[tid] = bias[gg * U_ + blk * 16 + j];
  }
  cst[tid] = 0.f;
  for (int i = tid; i < 1024; i += NTHR) { hph[i] = (_Float16)0.f; hpl[i] = (_Float16)0.f; }

  // Phase A weight B-fragments (split fp16) into registers.
  half8 bhi[2][2][4], blo[2][2][4];
  {
    const int n = lane & 15, q = lane >> 4;
#pragma unroll
    for (int c = 0; c < 2; ++c) {
      const float* Wsrc = c ? R : Wk;
#pragma unroll
      for (int nt = 0; nt < 2; ++nt) {
        int cib  = ch * 32 + nt * 16 + n;
        int gcol = (cib >> 4) * U_ + blk * 16 + (cib & 15);
#pragma unroll
        for (int u = 0; u < 4; ++u) {
          half8 th, tl;
#pragma unroll
          for (int i = 0; i < 8; ++i) {
            int k = (sq * 4 + u) * 32 + q * 8 + i;
            _Float16 hi, lo;
            split_h(Wsrc[(size_t)k * G4 + gcol], hi, lo);
            th[i] = hi; tl[i] = lo;
          }
          bhi[nt][c][u] = th;
          blo[nt][c][u] = tl;
        }
      }
    }
  }

  // Projection B-fragments: P rows blk*16..+15 (K padded to 32 with zeros).
  half8 psh[4], psl[4];
  {
    const int n = lane & 15, q = lane >> 4;
#pragma unroll
    for (int nt = 0; nt < 4; ++nt) {
      half8 th, tl;
#pragma unroll
      for (int i = 0; i < 8; ++i) { th[i] = (_Float16)0.f; tl[i] = (_Float16)0.f; }
      if (q < 2) {
#pragma unroll
        for (int i = 0; i < 8; ++i) {
          int k = q * 8 + i;                      // 0..15 real K
          _Float16 hi, lo;
          split_h(P[(size_t)(blk * 16 + k) * PJ + (w * 64 + nt * 16 + n)], hi, lo);
          th[i] = hi; tl[i] = lo;
        }
      }
      psh[nt] = th; psl[nt] = tl;
    }
  }
  __syncthreads();

  const int rb = blk >> 3;        // reduction duty: batch row
  const int rn = (blk & 7) << 6;  // reduction duty: col base (64 cols)
  const int o4 = tid & 15;        // reduce: col-quad
  const int gg = tid >> 4;        // reduce: partial-group 0..31
  const int m_ = lane & 15, q = lane >> 4;

  // ---- time loop ------------------------------------------------------
  for (int t = 0; t < S_; ++t) {
    floatx4 acc00 = {0.f, 0.f, 0.f, 0.f};
    floatx4 acc01 = acc00, acc10 = acc00, acc11 = acc00;
    floatx4 accL00 = acc00, accL01 = acc00, accL10 = acc00, accL11 = acc00;

    // ===== B1) stage x_t (independent of everything; hides producer tail) ==
#pragma unroll
    for (int it = 0; it < 4; ++it) {
      int c8 = tid + it * NTHR;
      int b  = c8 >> 6;
      int kg = (c8 & 63) << 3;
      const float* src = x + (size_t)(b * S_ + t) * D_ + kg;   // normal: cached
      floatx4 f0 = *(const floatx4*)src;
      floatx4 f1 = *(const floatx4*)(src + 4);
      half8 th, tl; _Float16 hi, lo;
      split_h(f0.x, hi, lo); th[0] = hi; tl[0] = lo;
      split_h(f0.y, hi, lo); th[1] = hi; tl[1] = lo;
      split_h(f0.z, hi, lo); th[2] = hi; tl[2] = lo;
      split_h(f0.w, hi, lo); th[3] = hi; tl[3] = lo;
      split_h(f1.x, hi, lo); th[4] = hi; tl[4] = lo;
      split_h(f1.y, hi, lo); th[5] = hi; tl[5] = lo;
      split_h(f1.z, hi, lo); th[6] = hi; tl[6] = lo;
      split_h(f1.w, hi, lo); th[7] = hi; tl[7] = lo;
      *(half8*)(xh_hi + b * PITC + kg) = th;
      *(half8*)(xh_lo + b * PITC + kg) = tl;
    }
    __syncthreads();

    // ===== A) reduction duty for step t-1 =====
    if (t > 0) {
      const unsigned e = (unsigned)t;
      if (w == 0) {
        for (;;) {
          uintx4 v = ld16u_sc1(flags1 + lane * 4);
          if (__all((int)(v.x >= e && v.y >= e && v.z >= e && v.w >= e))) break;
          __builtin_amdgcn_s_sleep(2);
        }
      }
      __syncthreads();
      {
        const float* pb = partial + (size_t)gg * 16384 + (size_t)rb * PJ + rn + o4 * 4;
        floatx4 r0, r1, r2, r3, r4, r5, r6, r7;
        asm volatile("global_load_dwordx4 %0, %1, off sc1" : "=v"(r0) : "v"(pb)           : "memory");
        asm volatile("global_load_dwordx4 %0, %1, off sc1" : "=v"(r1) : "v"(pb +  524288) : "memory");
        asm volatile("global_load_dwordx4 %0, %1, off sc1" : "=v"(r2) : "v"(pb + 1048576) : "memory");
        asm volatile("global_load_dwordx4 %0, %1, off sc1" : "=v"(r3) : "v"(pb + 1572864) : "memory");
        asm volatile("global_load_dwordx4 %0, %1, off sc1" : "=v"(r4) : "v"(pb + 2097152) : "memory");
        asm volatile("global_load_dwordx4 %0, %1, off sc1" : "=v"(r5) : "v"(pb + 2621440) : "memory");
        asm volatile("global_load_dwordx4 %0, %1, off sc1" : "=v"(r6) : "v"(pb + 3145728) : "memory");
        asm volatile("global_load_dwordx4 %0, %1, off sc1" : "=v"(r7) : "v"(pb + 3670016) : "memory");
        asm volatile("s_waitcnt vmcnt(0)" ::: "memory");
        __builtin_amdgcn_sched_barrier(0);
        floatx4 s = ((r0 + r1) + (r2 + r3)) + ((r4 + r5) + (r6 + r7));
        redf4[gg * 16 + o4] = s;
      }
      __syncthreads();
      if (tid < 16) {
        floatx4 a = redf4[tid];
#pragma unroll
        for (int g2 = 1; g2 < 32; ++g2) a += redf4[g2 * 16 + tid];
        a.x = fminf(fmaxf(a.x, -3.f), 3.f);
        a.y = fminf(fmaxf(a.y, -3.f), 3.f);
        a.z = fminf(fmaxf(a.z, -3.f), 3.f);
        a.w = fminf(fmaxf(a.w, -3.f), 3.f);
        store16_sc1(hbuf + (size_t)t * 16384 + (size_t)rb * PJ + rn + tid * 4, a);
        *(floatx4*)(out + ((size_t)rb * S_ + (t - 1)) * PJ + rn + tid * 4) = a;
      }
      __syncthreads();   // drain h-slice sc1 stores before h-ready flag
      if (tid == 0) stg_dev_u32(flags2 + blk, e);
    }

    // ===== B2) x MFMA (hides reducer tail) =====
#pragma unroll
    for (int u = 0; u < 4; ++u) {
      int ko = (sq * 4 + u) * 32 + q * 8;
      half8 ah0 = *(const half8*)(xh_hi + m_ * PITC + ko);
      half8 ah1 = *(const half8*)(xh_hi + (16 + m_) * PITC + ko);
      half8 al0 = *(const half8*)(xh_lo + m_ * PITC + ko);
      half8 al1 = *(const half8*)(xh_lo + (16 + m_) * PITC + ko);
      acc00 = __builtin_amdgcn_mfma_f32_16x16x32_f16(ah0, bhi[0][0][u], acc00, 0, 0, 0);
      acc01 = __builtin_amdgcn_mfma_f32_16x16x32_f16(ah0, bhi[1][0][u], acc01, 0, 0, 0);
      acc10 = __builtin_amdgcn_mfma_f32_16x16x32_f16(ah1, bhi[0][0][u], acc10, 0, 0, 0);
      acc11 = __builtin_amdgcn_mfma_f32_16x16x32_f16(ah1, bhi[1][0][u], acc11, 0, 0, 0);
      accL00 = __builtin_amdgcn_mfma_f32_16x16x32_f16(ah0, blo[0][0][u], accL00, 0, 0, 0);
      accL01 = __builtin_amdgcn_mfma_f32_16x16x32_f16(ah0, blo[1][0][u], accL01, 0, 0, 0);
      accL10 = __builtin_amdgcn_mfma_f32_16x16x32_f16(ah1, blo[0][0][u], accL10, 0, 0, 0);
      accL11 = __builtin_amdgcn_mfma_f32_16x16x32_f16(ah1, blo[1][0][u], accL11, 0, 0, 0);
      accL00 = __builtin_amdgcn_mfma_f32_16x16x32_f16(al0, bhi[0][0][u], accL00, 0, 0, 0);
      accL01 = __builtin_amdgcn_mfma_f32_16x16x32_f16(al0, bhi[1][0][u], accL01, 0, 0, 0);
      accL10 = __builtin_amdgcn_mfma_f32_16x16x32_f16(al1, bhi[0][0][u], accL10, 0, 0, 0);
      accL11 = __builtin_amdgcn_mfma_f32_16x16x32_f16(al1, bhi[1][0][u], accL11, 0, 0, 0);
    }

    // ===== C) wait h(t-1) ready =====
    if (t > 0) {
      if (w == 0) {
        const unsigned e = (unsigned)t;
        for (;;) {
          uintx4 v = ld16u_sc1(flags2 + lane * 4);
          if (__all((int)(v.x >= e && v.y >= e && v.z >= e && v.w >= e))) break;
          __builtin_amdgcn_s_sleep(2);
        }
      }
    }
    __syncthreads();   // protects xh from B2 readers before D overwrites

    // ===== D) stage h from ring slot t (NORMAL cached loads; L2-shared) =====
    {
      const float* hsl = hbuf + (size_t)t * 16384;
#pragma unroll
      for (int it = 0; it < 4; ++it) {
        int c8 = tid + it * NTHR;
        int b  = c8 >> 6;
        int kg = (c8 & 63) << 3;
        const float* src = hsl + b * PJ + kg;
        floatx4 f0 = *(const floatx4*)src;
        floatx4 f1 = *(const floatx4*)(src + 4);
        half8 th, tl; _Float16 hi, lo;
        split_h(f0.x, hi, lo); th[0] = hi; tl[0] = lo;
        split_h(f0.y, hi, lo); th[1] = hi; tl[1] = lo;
        split_h(f0.z, hi, lo); th[2] = hi; tl[2] = lo;
        split_h(f0.w, hi, lo); th[3] = hi; tl[3] = lo;
        split_h(f1.x, hi, lo); th[4] = hi; tl[4] = lo;
        split_h(f1.y, hi, lo); th[5] = hi; tl[5] = lo;
        split_h(f1.z, hi, lo); th[6] = hi; tl[6] = lo;
        split_h(f1.w, hi, lo); th[7] = hi; tl[7] = lo;
        *(half8*)(xh_hi + b * PITC + kg) = th;
        *(half8*)(xh_lo + b * PITC + kg) = tl;
      }
    }
    __syncthreads();
#pragma unroll
    for (int u = 0; u < 4; ++u) {
      int ko = (sq * 4 + u) * 32 + q * 8;
      half8 ah0 = *(const half8*)(xh_hi + m_ * PITC + ko);
      half8 ah1 = *(const half8*)(xh_hi + (16 + m_) * PITC + ko);
      half8 al0 = *(const half8*)(xh_lo + m_ * PITC + ko);
      half8 al1 = *(const half8*)(xh_lo + (16 + m_) * PITC + ko);
      acc00 = __builtin_amdgcn_mfma_f32_16x16x32_f16(ah0, bhi[0][1][u], acc00, 0, 0, 0);
      acc01 = __builtin_amdgcn_mfma_f32_16x16x32_f16(ah0, bhi[1][1][u], acc01, 0, 0, 0);
      acc10 = __builtin_amdgcn_mfma_f32_16x16x32_f16(ah1, bhi[0][1][u], acc10, 0, 0, 0);
      acc11 = __builtin_amdgcn_mfma_f32_16x16x32_f16(ah1, bhi[1][1][u], acc11, 0, 0, 0);
      accL00 = __builtin_amdgcn_mfma_f32_16x16x32_f16(ah0, blo[0][1][u], accL00, 0, 0, 0);
      accL01 = __builtin_amdgcn_mfma_f32_16x16x32_f16(ah0, blo[1][1][u], accL01, 0, 0, 0);
      accL10 = __builtin_amdgcn_mfma_f32_16x16x32_f16(ah1, blo[0][1][u], accL10, 0, 0, 0);
      accL11 = __builtin_amdgcn_mfma_f32_16x16x32_f16(ah1, blo[1][1][u], accL11, 0, 0, 0);
      accL00 = __builtin_amdgcn_mfma_f32_16x16x32_f16(al0, bhi[0][1][u], accL00, 0, 0, 0);
      accL01 = __builtin_amdgcn_mfma_f32_16x16x32_f16(al0, bhi[1][1][u], accL01, 0, 0, 0);
      accL10 = __builtin_amdgcn_mfma_f32_16x16x32_f16(al1, bhi[0][1][u], accL10, 0, 0, 0);
      accL11 = __builtin_amdgcn_mfma_f32_16x16x32_f16(al1, bhi[1][1][u], accL11, 0, 0, 0);
    }

    // D-frag -> zb[sq][col][batch]  (zb disjoint from xh)
    {
      int n  = lane & 15;
      int c0 = ch * 32 + n, c1 = ch * 32 + 16 + n;
      int r0 = q * 4,       r1 = 16 + q * 4;
#pragma unroll
      for (int i = 0; i < 4; ++i) {
        zb[sq][c0][r0 + i] = acc00[i] + accL00[i] * LINV;
        zb[sq][c1][r0 + i] = acc01[i] + accL01[i] * LINV;
        zb[sq][c0][r1 + i] = acc10[i] + accL10[i] * LINV;
        zb[sq][c1][r1 + i] = acc11[i] + accL11[i] * LINV;
      }
    }
    __syncthreads();

    // ===== E) gates + cell update; hp -> LDS split planes =====
    {
      int p = tid;                      // 0..511
      int b = p >> 4, j = p & 15;
      float zi = zb[0][j][b] + zb[1][j][b] + zb[2][j][b] + zb[3][j][b] + biasL[j];
      float zf = zb[0][16+j][b] + zb[1][16+j][b] + zb[2][16+j][b] + zb[3][16+j][b] + biasL[16+j];
      float zc = zb[0][32+j][b] + zb[1][32+j][b] + zb[2][32+j][b] + zb[3][32+j][b] + biasL[32+j];
      float zo = zb[0][48+j][b] + zb[1][48+j][b] + zb[2][48+j][b] + zb[3][48+j][b] + biasL[48+j];
      float ig = fminf(fmaxf(0.2f * zi + 0.5f, 0.f), 1.f);
      float fg = fminf(fmaxf(0.2f * zf + 0.5f, 0.f), 1.f);
      float og = fminf(fmaxf(0.2f * zo + 0.5f, 0.f), 1.f);
      float cn = fg * cst[p] + ig * tanhf(zc);
      float hp = og * tanhf(cn);                 // uses UNCLIPPED c
      cst[p] = fminf(fmaxf(cn, -3.f), 3.f);      // cell clip

      _Float16 hh, hl;
      split_h(hp, hh, hl);
      hph[b * 32 + j] = hh;
      hpl[b * 32 + j] = hl;
    }
    __syncthreads();   // hph/hpl visible; zb reads done; xh dead -> part_lds ok

    // ===== F) local projection partial -> part_lds (overlay xh) =====
    {
      floatx4 pa[2][4], pL[2][4];
#pragma unroll
      for (int mt = 0; mt < 2; ++mt)
#pragma unroll
        for (int nt = 0; nt < 4; ++nt) {
          pa[mt][nt] = (floatx4){0.f, 0.f, 0.f, 0.f};
          pL[mt][nt] = (floatx4){0.f, 0.f, 0.f, 0.f};
        }
#pragma unroll
      for (int mt = 0; mt < 2; ++mt) {
        half8 ah = *(const half8*)(hph + (mt * 16 + m_) * 32 + q * 8);
        half8 al = *(const half8*)(hpl + (mt * 16 + m_) * 32 + q * 8);
#pragma unroll
        for (int nt = 0; nt < 4; ++nt) {
          pa[mt][nt] = __builtin_amdgcn_mfma_f32_16x16x32_f16(ah, psh[nt], pa[mt][nt], 0, 0, 0);
          pL[mt][nt] = __builtin_amdgcn_mfma_f32_16x16x32_f16(ah, psl[nt], pL[mt][nt], 0, 0, 0);
          pL[mt][nt] = __builtin_amdgcn_mfma_f32_16x16x32_f16(al, psh[nt], pL[mt][nt], 0, 0, 0);
        }
      }
#pragma unroll
      for (int mt = 0; mt < 2; ++mt)
#pragma unroll
        for (int nt = 0; nt < 4; ++nt)
#pragma unroll
          for (int i = 0; i < 4; ++i) {
            float v = pa[mt][nt][i] + pL[mt][nt][i] * LINV;
            part_lds[(mt * 16 + q * 4 + i) * PJ + w * 64 + nt * 16 + m_] = v;
          }
    }
    __syncthreads();
    // coalesced 16B sc1 copy of the 64KB f32 partial
    {
      const floatx4* srcv = (const floatx4*)part_lds;
      float* dst = partial + (size_t)blk * 16384;
#pragma unroll
      for (int kk = 0; kk < 8; ++kk)
        store16_sc1(dst + kk * 2048 + tid * 4, srcv[kk * 512 + tid]);
    }
    __syncthreads();   // drain partial stores before flag
    if (tid == 0) stg_dev_u32(flags1 + blk, (unsigned)(t + 1));
  }

  // ===== epilogue: reduction duty for t = S_-1 (out only) =====
  {
    const unsigned e = (unsigned)S_;
    if (w == 0) {
      for (;;) {
        uintx4 v = ld16u_sc1(flags1 + lane * 4);
        if (__all((int)(v.x >= e && v.y >= e && v.z >= e && v.w >= e))) break;
        __builtin_amdgcn_s_sleep(2);
      }
    }
    __syncthreads();
    {
      const float* pb = partial + (size_t)gg * 16384 + (size_t)rb * PJ + rn + o4 * 4;
      floatx4 r0, r1, r2, r3, r4, r5, r6, r7;
      asm volatile("global_load_dwordx4 %0, %1, off sc1" : "=v"(r0) : "v"(pb)           : "memory");
      asm volatile("global_load_dwordx4 %0, %1, off sc1" : "=v"(r1) : "v"(pb +  524288) : "memory");
      asm volatile("global_load_dwordx4 %0, %1, off sc1" : "=v"(r2) : "v"(pb + 1048576) : "memory");
      asm volatile("global_load_dwordx4 %0, %1, off sc1" : "=v"(r3) : "v"(pb + 1572864) : "memory");
      asm volatile("global_load_dwordx4 %0, %1, off sc1" : "=v"(r4) : "v"(pb + 2097152) : "memory");
      asm volatile("global_load_dwordx4 %0, %1, off sc1" : "=v"(r5) : "v"(pb + 2621440) : "memory");
      asm volatile("global_load_dwordx4 %0, %1, off sc1" : "=v"(r6) : "v"(pb + 3145728) : "memory");
      asm volatile("global_load_dwordx4 %0, %1, off sc1" : "=v"(r7) : "v"(pb + 3670016) : "memory");
      asm volatile("s_waitcnt vmcnt(0)" ::: "memory");
      __builtin_amdgcn_sched_barrier(0);
      floatx4 s = ((r0 + r1) + (r2 + r3)) + ((r4 + r5) + (r6 + r7));
      redf4[gg * 16 + o4] = s;
    }
    __syncthreads();
    if (tid < 16) {
      floatx4 a = redf4[tid];
#pragma unroll
      for (int g2 = 1; g2 < 32; ++g2) a += redf4[g2 * 16 + tid];
      a.x = fminf(fmaxf(a.x, -3.f), 3.f);
      a.y = fminf(fmaxf(a.y, -3.f), 3.f);
      a.z = fminf(fmaxf(a.z, -3.f), 3.f);
      a.w = fminf(fmaxf(a.w, -3.f), 3.f);
      *(floatx4*)(out + ((size_t)rb * S_ + (S_ - 1)) * PJ + rn + tid * 4) = a;
    }
  }
}

extern "C" void kernel_launch(void* const* d_in, const int* in_sizes, int n_in,
                              void* d_out, int out_size, void* d_ws, size_t ws_size,
                              hipStream_t stream) {
  const float* x_   = (const float*)d_in[0];
  const float* Wk   = (const float*)d_in[1];
  const float* R_   = (const float*)d_in[2];
  const float* bias = (const float*)d_in[3];
  const float* P_   = (const float*)d_in[4];
  float* out = (float*)d_out;

  unsigned char* ws = (unsigned char*)d_ws;
  unsigned* flags1 = (unsigned*)ws;                   // 1 KB
  unsigned* flags2 = (unsigned*)(ws + 4096);          // 1 KB
  float* hbuf      = (float*)(ws + 16384);            // ring: 128 x 64KB = 8 MB
  float* partial   = (float*)(ws + 16384 + 8388608);  // 16 MB f32 partials

  // zero flags + hbuf slot 0 (h(-1) = 0) every launch
  (void)hipMemsetAsync(d_ws, 0, 16384 + 65536, stream);

  lstm_persistent<<<dim3(NBLK), dim3(NTHR), 0, stream>>>(
      x_, Wk, R_, bias, P_, out, flags1, flags2, hbuf, partial);
}

// Round 5
// 2574.958 us; speedup vs baseline: 2.2107x; 1.0343x over previous
//
#include <hip/hip_runtime.h>

// LSTM-with-projection (ELMo LSTMP), persistent-kernel, fp32-class precision.
// Round 13: keep r12 architecture (rank-16 f32 partials + flat 256-block
// reduction, 2 hops), attack SERIALIZATION:
//  1. Read-behind-write: per-load flag gating (8-flag precheck, fast path
//     issues all 8 partial reads at once) instead of a global all-256 wait.
//  2. x-MFMA (B2) interleaved INTO the A-phase: u0/u1 between load-issue and
//     vmcnt(0) (hides LLC read latency), u2/u3 after the h-flag (off the
//     global critical path). vmcnt(0)+sched_barrier(0) before consuming loads.
//  3. Parallel reduction tree (128 threads -> 16).
//  4. h-ring stores PACKED split-f16 (hi|lo<<16 u32): bit-identical to the
//     split D computed before -> D's per-element split (6 VALU) becomes
//     2 bit-ops; zero precision change.

#define NBLK 256
#define NTHR 512
#define B_   32
#define S_   128
#define D_   512
#define U_   4096
#define PJ   512
#define G4   16384
#define PITC 520
#define LSCALE 2048.0f
#define LINV   4.8828125e-4f   // 1/2048

typedef __attribute__((ext_vector_type(8))) _Float16 half8;
typedef __attribute__((ext_vector_type(4))) float floatx4;
typedef __attribute__((ext_vector_type(4))) unsigned int uintx4;

__device__ __forceinline__ void split_h(float f, _Float16& hi, _Float16& lo) {
  _Float16 h = (_Float16)f;                  // RTNE
  hi = h;
  lo = (_Float16)((f - (float)h) * LSCALE);  // residual x2048: fp16-normal
}

// ---- agent-scope (sc1) ops: LLC-coherent ----
__device__ __forceinline__ void stg_dev_u32(unsigned* p, unsigned v) {
  __hip_atomic_store(p, v, __ATOMIC_RELAXED, __HIP_MEMORY_SCOPE_AGENT);
}
__device__ __forceinline__ unsigned ldg_dev_u32(const unsigned* p) {
  return __hip_atomic_load(p, __ATOMIC_RELAXED, __HIP_MEMORY_SCOPE_AGENT);
}
__device__ __forceinline__ void store16_sc1(float* p, floatx4 v) {
  asm volatile("global_store_dwordx4 %0, %1, off sc1" :: "v"(p), "v"(v) : "memory");
}
__device__ __forceinline__ void store16u_sc1(unsigned* p, uintx4 v) {
  asm volatile("global_store_dwordx4 %0, %1, off sc1" :: "v"(p), "v"(v) : "memory");
}
__device__ __forceinline__ uintx4 ld16u_sc1(const unsigned* p) {
  uintx4 r;
  asm volatile("global_load_dwordx4 %0, %1, off sc1\n\ts_waitcnt vmcnt(0)"
               : "=v"(r) : "v"(p) : "memory");
  return r;
}

__global__ __launch_bounds__(NTHR, 2)
void lstm_persistent(const float* __restrict__ x,
                     const float* __restrict__ Wk,
                     const float* __restrict__ R,
                     const float* __restrict__ bias,
                     const float* __restrict__ P,
                     float* __restrict__ out,
                     unsigned* __restrict__ flags1,   // [256] u32: partial ready
                     unsigned* __restrict__ flags2,   // [256] u32: h ready
                     unsigned* __restrict__ hring,    // ring [128][32][512] u32 packed
                     float* __restrict__ partial)     // f32 [256][32][512]
{
  __shared__ __align__(16) char smem[100352];
  _Float16* xh_hi = (_Float16*)smem;                        // 32*520 halves
  _Float16* xh_lo = xh_hi + B_ * PITC;
  float (*zb)[64][33] = (float (*)[64][33])(smem + 66560);  // [4][64][33]
  float* part_lds = (float*)smem;            // overlays xh (64KB), phase F only
  __shared__ float cst[512];
  __shared__ float biasL[64];
  __shared__ _Float16 hph[1024], hpl[1024];  // hp split planes [32][32], k>=16 = 0
  __shared__ floatx4 redf4[512];             // [32 gg][16 o4] reduction scratch

  const int tid  = threadIdx.x;
  const int blk  = blockIdx.x;
  const int lane = tid & 63;
  const int w    = tid >> 6;   // wave 0..7
  const int ch   = w & 1;      // phase A col-half
  const int sq   = w >> 1;     // phase A k-quarter

  // ---- one-time setup -------------------------------------------------
  if (tid < 64) {
    int gg = tid >> 4, j = tid & 15;
    biasL[tid] = bias[gg * U_ + blk * 16 + j];
  }
  cst[tid] = 0.f;
  for (int i = tid; i < 1024; i += NTHR) { hph[i] = (_Float16)0.f; hpl[i] = (_Float16)0.f; }

  // Phase A weight B-fragments (split fp16) into registers.
  half8 bhi[2][2][4], blo[2][2][4];
  {
    const int n = lane & 15, q = lane >> 4;
#pragma unroll
    for (int c = 0; c < 2; ++c) {
      const float* Wsrc = c ? R : Wk;
#pragma unroll
      for (int nt = 0; nt < 2; ++nt) {
        int cib  = ch * 32 + nt * 16 + n;
        int gcol = (cib >> 4) * U_ + blk * 16 + (cib & 15);
#pragma unroll
        for (int u = 0; u < 4; ++u) {
          half8 th, tl;
#pragma unroll
          for (int i = 0; i < 8; ++i) {
            int k = (sq * 4 + u) * 32 + q * 8 + i;
            _Float16 hi, lo;
            split_h(Wsrc[(size_t)k * G4 + gcol], hi, lo);
            th[i] = hi; tl[i] = lo;
          }
          bhi[nt][c][u] = th;
          blo[nt][c][u] = tl;
        }
      }
    }
  }

  // Projection B-fragments: P rows blk*16..+15 (K padded to 32 with zeros).
  half8 psh[4], psl[4];
  {
    const int n = lane & 15, q = lane >> 4;
#pragma unroll
    for (int nt = 0; nt < 4; ++nt) {
      half8 th, tl;
#pragma unroll
      for (int i = 0; i < 8; ++i) { th[i] = (_Float16)0.f; tl[i] = (_Float16)0.f; }
      if (q < 2) {
#pragma unroll
        for (int i = 0; i < 8; ++i) {
          int k = q * 8 + i;                      // 0..15 real K
          _Float16 hi, lo;
          split_h(P[(size_t)(blk * 16 + k) * PJ + (w * 64 + nt * 16 + n)], hi, lo);
          th[i] = hi; tl[i] = lo;
        }
      }
      psh[nt] = th; psl[nt] = tl;
    }
  }
  __syncthreads();

  const int rb = blk >> 3;        // reduction duty: batch row
  const int rn = (blk & 7) << 6;  // reduction duty: col base (64 cols)
  const int o4 = tid & 15;        // reduce: col-quad
  const int gg = tid >> 4;        // reduce: partial-group 0..31
  const int m_ = lane & 15, q = lane >> 4;

// One u-iteration of the x-part MFMA (literal U -> static reg indexing).
#define B2U(U) do {                                                            \
    int ko = (sq * 4 + (U)) * 32 + q * 8;                                      \
    half8 ah0 = *(const half8*)(xh_hi + m_ * PITC + ko);                       \
    half8 ah1 = *(const half8*)(xh_hi + (16 + m_) * PITC + ko);                \
    half8 al0 = *(const half8*)(xh_lo + m_ * PITC + ko);                       \
    half8 al1 = *(const half8*)(xh_lo + (16 + m_) * PITC + ko);                \
    acc00 = __builtin_amdgcn_mfma_f32_16x16x32_f16(ah0, bhi[0][0][U], acc00, 0, 0, 0); \
    acc01 = __builtin_amdgcn_mfma_f32_16x16x32_f16(ah0, bhi[1][0][U], acc01, 0, 0, 0); \
    acc10 = __builtin_amdgcn_mfma_f32_16x16x32_f16(ah1, bhi[0][0][U], acc10, 0, 0, 0); \
    acc11 = __builtin_amdgcn_mfma_f32_16x16x32_f16(ah1, bhi[1][0][U], acc11, 0, 0, 0); \
    accL00 = __builtin_amdgcn_mfma_f32_16x16x32_f16(ah0, blo[0][0][U], accL00, 0, 0, 0); \
    accL01 = __builtin_amdgcn_mfma_f32_16x16x32_f16(ah0, blo[1][0][U], accL01, 0, 0, 0); \
    accL10 = __builtin_amdgcn_mfma_f32_16x16x32_f16(ah1, blo[0][0][U], accL10, 0, 0, 0); \
    accL11 = __builtin_amdgcn_mfma_f32_16x16x32_f16(ah1, blo[1][0][U], accL11, 0, 0, 0); \
    accL00 = __builtin_amdgcn_mfma_f32_16x16x32_f16(al0, bhi[0][0][U], accL00, 0, 0, 0); \
    accL01 = __builtin_amdgcn_mfma_f32_16x16x32_f16(al0, bhi[1][0][U], accL01, 0, 0, 0); \
    accL10 = __builtin_amdgcn_mfma_f32_16x16x32_f16(al1, bhi[0][0][U], accL10, 0, 0, 0); \
    accL11 = __builtin_amdgcn_mfma_f32_16x16x32_f16(al1, bhi[1][0][U], accL11, 0, 0, 0); \
  } while (0)

#define SPIN1(Rr) for (;;) { unsigned vv = ldg_dev_u32(flags1 + (Rr) * 32 + gg); \
                             if (__all((int)(vv >= e))) break;                   \
                             __builtin_amdgcn_s_sleep(2); }

  // ---- time loop ------------------------------------------------------
  for (int t = 0; t < S_; ++t) {
    floatx4 acc00 = {0.f, 0.f, 0.f, 0.f};
    floatx4 acc01 = acc00, acc10 = acc00, acc11 = acc00;
    floatx4 accL00 = acc00, accL01 = acc00, accL10 = acc00, accL11 = acc00;

    // ===== B1) stage x_t =====
#pragma unroll
    for (int it = 0; it < 4; ++it) {
      int c8 = tid + it * NTHR;
      int b  = c8 >> 6;
      int kg = (c8 & 63) << 3;
      const float* src = x + (size_t)(b * S_ + t) * D_ + kg;   // normal: cached
      floatx4 f0 = *(const floatx4*)src;
      floatx4 f1 = *(const floatx4*)(src + 4);
      half8 th, tl; _Float16 hi, lo;
      split_h(f0.x, hi, lo); th[0] = hi; tl[0] = lo;
      split_h(f0.y, hi, lo); th[1] = hi; tl[1] = lo;
      split_h(f0.z, hi, lo); th[2] = hi; tl[2] = lo;
      split_h(f0.w, hi, lo); th[3] = hi; tl[3] = lo;
      split_h(f1.x, hi, lo); th[4] = hi; tl[4] = lo;
      split_h(f1.y, hi, lo); th[5] = hi; tl[5] = lo;
      split_h(f1.z, hi, lo); th[6] = hi; tl[6] = lo;
      split_h(f1.w, hi, lo); th[7] = hi; tl[7] = lo;
      *(half8*)(xh_hi + b * PITC + kg) = th;
      *(half8*)(xh_lo + b * PITC + kg) = tl;
    }
    __syncthreads();

    // ===== A) reduction duty for step t-1, interleaved with B2 =====
    if (t > 0) {
      const unsigned e = (unsigned)t;
      const float* pbase = partial + (size_t)gg * 16384 + (size_t)rb * PJ + rn + o4 * 4;
      floatx4 r0, r1, r2, r3, r4, r5, r6, r7;
      // fast precheck: this thread's 8 producer flags
      unsigned f0 = ldg_dev_u32(flags1 + gg);
      unsigned f1 = ldg_dev_u32(flags1 + 32 + gg);
      unsigned f2 = ldg_dev_u32(flags1 + 64 + gg);
      unsigned f3 = ldg_dev_u32(flags1 + 96 + gg);
      unsigned f4 = ldg_dev_u32(flags1 + 128 + gg);
      unsigned f5 = ldg_dev_u32(flags1 + 160 + gg);
      unsigned f6 = ldg_dev_u32(flags1 + 192 + gg);
      unsigned f7 = ldg_dev_u32(flags1 + 224 + gg);
      bool rdy = (f0 >= e) && (f1 >= e) && (f2 >= e) && (f3 >= e) &&
                 (f4 >= e) && (f5 >= e) && (f6 >= e) && (f7 >= e);
      const bool allrdy = __all((int)rdy);
      if (!allrdy) SPIN1(0)
      asm volatile("global_load_dwordx4 %0, %1, off sc1" : "=v"(r0) : "v"(pbase)           : "memory");
      if (!allrdy) SPIN1(1)
      asm volatile("global_load_dwordx4 %0, %1, off sc1" : "=v"(r1) : "v"(pbase +  524288) : "memory");
      if (!allrdy) SPIN1(2)
      asm volatile("global_load_dwordx4 %0, %1, off sc1" : "=v"(r2) : "v"(pbase + 1048576) : "memory");
      if (!allrdy) SPIN1(3)
      asm volatile("global_load_dwordx4 %0, %1, off sc1" : "=v"(r3) : "v"(pbase + 1572864) : "memory");
      if (!allrdy) SPIN1(4)
      asm volatile("global_load_dwordx4 %0, %1, off sc1" : "=v"(r4) : "v"(pbase + 2097152) : "memory");
      if (!allrdy) SPIN1(5)
      asm volatile("global_load_dwordx4 %0, %1, off sc1" : "=v"(r5) : "v"(pbase + 2621440) : "memory");
      if (!allrdy) SPIN1(6)
      asm volatile("global_load_dwordx4 %0, %1, off sc1" : "=v"(r6) : "v"(pbase + 3145728) : "memory");
      if (!allrdy) SPIN1(7)
      asm volatile("global_load_dwordx4 %0, %1, off sc1" : "=v"(r7) : "v"(pbase + 3670016) : "memory");
      // hide load latency under x-MFMA
      B2U(0); B2U(1);
      asm volatile("s_waitcnt vmcnt(0)" ::: "memory");
      __builtin_amdgcn_sched_barrier(0);
      floatx4 s = ((r0 + r1) + (r2 + r3)) + ((r4 + r5) + (r6 + r7));
      redf4[gg * 16 + o4] = s;
      __syncthreads();
      // parallel tree: 128 threads fold 32 groups -> 8, then 16 finish
      if (tid < 128) {
        int ob = tid & 15, g8 = tid >> 4;   // g8 0..7
        floatx4 a = redf4[g8 * 16 + ob] + redf4[(g8 + 8) * 16 + ob] +
                    redf4[(g8 + 16) * 16 + ob] + redf4[(g8 + 24) * 16 + ob];
        redf4[g8 * 16 + ob] = a;            // same-thread read->write only
      }
      __syncthreads();
      if (tid < 16) {
        floatx4 a = redf4[tid];
#pragma unroll
        for (int g8 = 1; g8 < 8; ++g8) a += redf4[g8 * 16 + tid];
        a.x = fminf(fmaxf(a.x, -3.f), 3.f);
        a.y = fminf(fmaxf(a.y, -3.f), 3.f);
        a.z = fminf(fmaxf(a.z, -3.f), 3.f);
        a.w = fminf(fmaxf(a.w, -3.f), 3.f);
        // pack split-f16 (bit-identical to consumer-side split)
        uintx4 pk;
#pragma unroll
        for (int i = 0; i < 4; ++i) {
          _Float16 hh, hl;
          split_h(a[i], hh, hl);
          pk[i] = (unsigned)__builtin_bit_cast(unsigned short, hh) |
                  ((unsigned)__builtin_bit_cast(unsigned short, hl) << 16);
        }
        store16u_sc1(hring + (size_t)t * 16384 + (size_t)rb * PJ + rn + tid * 4, pk);
        *(floatx4*)(out + ((size_t)rb * S_ + (t - 1)) * PJ + rn + tid * 4) = a;
      }
      __syncthreads();   // drain h-slice sc1 stores before h-ready flag
      if (tid == 0) stg_dev_u32(flags2 + blk, e);
      // remaining x-MFMA off the global critical path
      B2U(2); B2U(3);
    } else {
      B2U(0); B2U(1); B2U(2); B2U(3);
    }

    // ===== C) wait h(t-1) ready =====
    if (t > 0) {
      if (w == 0) {
        const unsigned e = (unsigned)t;
        for (;;) {
          uintx4 v = ld16u_sc1(flags2 + lane * 4);
          if (__all((int)(v.x >= e && v.y >= e && v.z >= e && v.w >= e))) break;
          __builtin_amdgcn_s_sleep(2);
        }
      }
    }
    __syncthreads();   // protects xh from B2 readers before D overwrites

    // ===== D) stage h from ring slot t (NORMAL cached loads; packed) =====
    {
      const unsigned* hsl = hring + (size_t)t * 16384;
#pragma unroll
      for (int it = 0; it < 4; ++it) {
        int c8 = tid + it * NTHR;
        int b  = c8 >> 6;
        int kg = (c8 & 63) << 3;
        const unsigned* src = hsl + b * PJ + kg;
        uintx4 v0 = *(const uintx4*)src;
        uintx4 v1 = *(const uintx4*)(src + 4);
        half8 th, tl;
        th[0] = __builtin_bit_cast(_Float16, (unsigned short)(v0.x & 0xffffu));
        tl[0] = __builtin_bit_cast(_Float16, (unsigned short)(v0.x >> 16));
        th[1] = __builtin_bit_cast(_Float16, (unsigned short)(v0.y & 0xffffu));
        tl[1] = __builtin_bit_cast(_Float16, (unsigned short)(v0.y >> 16));
        th[2] = __builtin_bit_cast(_Float16, (unsigned short)(v0.z & 0xffffu));
        tl[2] = __builtin_bit_cast(_Float16, (unsigned short)(v0.z >> 16));
        th[3] = __builtin_bit_cast(_Float16, (unsigned short)(v0.w & 0xffffu));
        tl[3] = __builtin_bit_cast(_Float16, (unsigned short)(v0.w >> 16));
        th[4] = __builtin_bit_cast(_Float16, (unsigned short)(v1.x & 0xffffu));
        tl[4] = __builtin_bit_cast(_Float16, (unsigned short)(v1.x >> 16));
        th[5] = __builtin_bit_cast(_Float16, (unsigned short)(v1.y & 0xffffu));
        tl[5] = __builtin_bit_cast(_Float16, (unsigned short)(v1.y >> 16));
        th[6] = __builtin_bit_cast(_Float16, (unsigned short)(v1.z & 0xffffu));
        tl[6] = __builtin_bit_cast(_Float16, (unsigned short)(v1.z >> 16));
        th[7] = __builtin_bit_cast(_Float16, (unsigned short)(v1.w & 0xffffu));
        tl[7] = __builtin_bit_cast(_Float16, (unsigned short)(v1.w >> 16));
        *(half8*)(xh_hi + b * PITC + kg) = th;
        *(half8*)(xh_lo + b * PITC + kg) = tl;
      }
    }
    __syncthreads();
#pragma unroll
    for (int u = 0; u < 4; ++u) {
      int ko = (sq * 4 + u) * 32 + q * 8;
      half8 ah0 = *(const half8*)(xh_hi + m_ * PITC + ko);
      half8 ah1 = *(const half8*)(xh_hi + (16 + m_) * PITC + ko);
      half8 al0 = *(const half8*)(xh_lo + m_ * PITC + ko);
      half8 al1 = *(const half8*)(xh_lo + (16 + m_) * PITC + ko);
      acc00 = __builtin_amdgcn_mfma_f32_16x16x32_f16(ah0, bhi[0][1][u], acc00, 0, 0, 0);
      acc01 = __builtin_amdgcn_mfma_f32_16x16x32_f16(ah0, bhi[1][1][u], acc01, 0, 0, 0);
      acc10 = __builtin_amdgcn_mfma_f32_16x16x32_f16(ah1, bhi[0][1][u], acc10, 0, 0, 0);
      acc11 = __builtin_amdgcn_mfma_f32_16x16x32_f16(ah1, bhi[1][1][u], acc11, 0, 0, 0);
      accL00 = __builtin_amdgcn_mfma_f32_16x16x32_f16(ah0, blo[0][1][u], accL00, 0, 0, 0);
      accL01 = __builtin_amdgcn_mfma_f32_16x16x32_f16(ah0, blo[1][1][u], accL01, 0, 0, 0);
      accL10 = __builtin_amdgcn_mfma_f32_16x16x32_f16(ah1, blo[0][1][u], accL10, 0, 0, 0);
      accL11 = __builtin_amdgcn_mfma_f32_16x16x32_f16(ah1, blo[1][1][u], accL11, 0, 0, 0);
      accL00 = __builtin_amdgcn_mfma_f32_16x16x32_f16(al0, bhi[0][1][u], accL00, 0, 0, 0);
      accL01 = __builtin_amdgcn_mfma_f32_16x16x32_f16(al0, bhi[1][1][u], accL01, 0, 0, 0);
      accL10 = __builtin_amdgcn_mfma_f32_16x16x32_f16(al1, bhi[0][1][u], accL10, 0, 0, 0);
      accL11 = __builtin_amdgcn_mfma_f32_16x16x32_f16(al1, bhi[1][1][u], accL11, 0, 0, 0);
    }

    // D-frag -> zb[sq][col][batch]  (zb disjoint from xh)
    {
      int n  = lane & 15;
      int c0 = ch * 32 + n, c1 = ch * 32 + 16 + n;
      int r0 = q * 4,       r1 = 16 + q * 4;
#pragma unroll
      for (int i = 0; i < 4; ++i) {
        zb[sq][c0][r0 + i] = acc00[i] + accL00[i] * LINV;
        zb[sq][c1][r0 + i] = acc01[i] + accL01[i] * LINV;
        zb[sq][c0][r1 + i] = acc10[i] + accL10[i] * LINV;
        zb[sq][c1][r1 + i] = acc11[i] + accL11[i] * LINV;
      }
    }
    __syncthreads();

    // ===== E) gates + cell update; hp -> LDS split planes =====
    {
      int p = tid;                      // 0..511
      int b = p >> 4, j = p & 15;
      float zi = zb[0][j][b] + zb[1][j][b] + zb[2][j][b] + zb[3][j][b] + biasL[j];
      float zf = zb[0][16+j][b] + zb[1][16+j][b] + zb[2][16+j][b] + zb[3][16+j][b] + biasL[16+j];
      float zc = zb[0][32+j][b] + zb[1][32+j][b] + zb[2][32+j][b] + zb[3][32+j][b] + biasL[32+j];
      float zo = zb[0][48+j][b] + zb[1][48+j][b] + zb[2][48+j][b] + zb[3][48+j][b] + biasL[48+j];
      float ig = fminf(fmaxf(0.2f * zi + 0.5f, 0.f), 1.f);
      float fg = fminf(fmaxf(0.2f * zf + 0.5f, 0.f), 1.f);
      float og = fminf(fmaxf(0.2f * zo + 0.5f, 0.f), 1.f);
      float cn = fg * cst[p] + ig * tanhf(zc);
      float hp = og * tanhf(cn);                 // uses UNCLIPPED c
      cst[p] = fminf(fmaxf(cn, -3.f), 3.f);      // cell clip

      _Float16 hh, hl;
      split_h(hp, hh, hl);
      hph[b * 32 + j] = hh;
      hpl[b * 32 + j] = hl;
    }
    __syncthreads();   // hph/hpl visible; zb reads done; xh dead -> part_lds ok

    // ===== F) local projection partial -> part_lds (overlay xh) =====
    {
      floatx4 pa[2][4], pL[2][4];
#pragma unroll
      for (int mt = 0; mt < 2; ++mt)
#pragma unroll
        for (int nt = 0; nt < 4; ++nt) {
          pa[mt][nt] = (floatx4){0.f, 0.f, 0.f, 0.f};
          pL[mt][nt] = (floatx4){0.f, 0.f, 0.f, 0.f};
        }
#pragma unroll
      for (int mt = 0; mt < 2; ++mt) {
        half8 ah = *(const half8*)(hph + (mt * 16 + m_) * 32 + q * 8);
        half8 al = *(const half8*)(hpl + (mt * 16 + m_) * 32 + q * 8);
#pragma unroll
        for (int nt = 0; nt < 4; ++nt) {
          pa[mt][nt] = __builtin_amdgcn_mfma_f32_16x16x32_f16(ah, psh[nt], pa[mt][nt], 0, 0, 0);
          pL[mt][nt] = __builtin_amdgcn_mfma_f32_16x16x32_f16(ah, psl[nt], pL[mt][nt], 0, 0, 0);
          pL[mt][nt] = __builtin_amdgcn_mfma_f32_16x16x32_f16(al, psh[nt], pL[mt][nt], 0, 0, 0);
        }
      }
#pragma unroll
      for (int mt = 0; mt < 2; ++mt)
#pragma unroll
        for (int nt = 0; nt < 4; ++nt)
#pragma unroll
          for (int i = 0; i < 4; ++i) {
            float v = pa[mt][nt][i] + pL[mt][nt][i] * LINV;
            part_lds[(mt * 16 + q * 4 + i) * PJ + w * 64 + nt * 16 + m_] = v;
          }
    }
    __syncthreads();
    // coalesced 16B sc1 copy of the 64KB f32 partial
    {
      const floatx4* srcv = (const floatx4*)part_lds;
      float* dst = partial + (size_t)blk * 16384;
#pragma unroll
      for (int kk = 0; kk < 8; ++kk)
        store16_sc1(dst + kk * 2048 + tid * 4, srcv[kk * 512 + tid]);
    }
    __syncthreads();   // drain partial stores before flag
    if (tid == 0) stg_dev_u32(flags1 + blk, (unsigned)(t + 1));
  }

  // ===== epilogue: reduction duty for t = S_-1 (out only) =====
  {
    const unsigned e = (unsigned)S_;
    if (w == 0) {
      for (;;) {
        uintx4 v = ld16u_sc1(flags1 + lane * 4);
        if (__all((int)(v.x >= e && v.y >= e && v.z >= e && v.w >= e))) break;
        __builtin_amdgcn_s_sleep(2);
      }
    }
    __syncthreads();
    {
      const float* pb = partial + (size_t)gg * 16384 + (size_t)rb * PJ + rn + o4 * 4;
      floatx4 r0, r1, r2, r3, r4, r5, r6, r7;
      asm volatile("global_load_dwordx4 %0, %1, off sc1" : "=v"(r0) : "v"(pb)           : "memory");
      asm volatile("global_load_dwordx4 %0, %1, off sc1" : "=v"(r1) : "v"(pb +  524288) : "memory");
      asm volatile("global_load_dwordx4 %0, %1, off sc1" : "=v"(r2) : "v"(pb + 1048576) : "memory");
      asm volatile("global_load_dwordx4 %0, %1, off sc1" : "=v"(r3) : "v"(pb + 1572864) : "memory");
      asm volatile("global_load_dwordx4 %0, %1, off sc1" : "=v"(r4) : "v"(pb + 2097152) : "memory");
      asm volatile("global_load_dwordx4 %0, %1, off sc1" : "=v"(r5) : "v"(pb + 2621440) : "memory");
      asm volatile("global_load_dwordx4 %0, %1, off sc1" : "=v"(r6) : "v"(pb + 3145728) : "memory");
      asm volatile("global_load_dwordx4 %0, %1, off sc1" : "=v"(r7) : "v"(pb + 3670016) : "memory");
      asm volatile("s_waitcnt vmcnt(0)" ::: "memory");
      __builtin_amdgcn_sched_barrier(0);
      floatx4 s = ((r0 + r1) + (r2 + r3)) + ((r4 + r5) + (r6 + r7));
      redf4[gg * 16 + o4] = s;
    }
    __syncthreads();
    if (tid < 16) {
      floatx4 a = redf4[tid];
#pragma unroll
      for (int g2 = 1; g2 < 32; ++g2) a += redf4[g2 * 16 + tid];
      a.x = fminf(fmaxf(a.x, -3.f), 3.f);
      a.y = fminf(fmaxf(a.y, -3.f), 3.f);
      a.z = fminf(fmaxf(a.z, -3.f), 3.f);
      a.w = fminf(fmaxf(a.w, -3.f), 3.f);
      *(floatx4*)(out + ((size_t)rb * S_ + (S_ - 1)) * PJ + rn + tid * 4) = a;
    }
  }
}

extern "C" void kernel_launch(void* const* d_in, const int* in_sizes, int n_in,
                              void* d_out, int out_size, void* d_ws, size_t ws_size,
                              hipStream_t stream) {
  const float* x_   = (const float*)d_in[0];
  const float* Wk   = (const float*)d_in[1];
  const float* R_   = (const float*)d_in[2];
  const float* bias = (const float*)d_in[3];
  const float* P_   = (const float*)d_in[4];
  float* out = (float*)d_out;

  unsigned char* ws = (unsigned char*)d_ws;
  unsigned* flags1 = (unsigned*)ws;                   // 1 KB
  unsigned* flags2 = (unsigned*)(ws + 4096);          // 1 KB
  unsigned* hring  = (unsigned*)(ws + 16384);         // ring: 128 x 64KB = 8 MB
  float* partial   = (float*)(ws + 16384 + 8388608);  // 16 MB f32 partials

  // zero flags + hring slot 0 (h(-1) = 0) every launch
  (void)hipMemsetAsync(d_ws, 0, 16384 + 65536, stream);

  lstm_persistent<<<dim3(NBLK), dim3(NTHR), 0, stream>>>(
      x_, Wk, R_, bias, P_, out, flags1, flags2, hring, partial);
}